// Round 3
// baseline (65.977 us; speedup 1.0000x reference)
//
#include <hip/hip_runtime.h>
#include <hip/hip_bf16.h>
#include <math.h>

// ImplicitPolygonInjector: B=4, C=128, H=W=64, S=4
// out[b][j][h*4+sy][w*4+sx] = (relu(hf[b,h,w,:] + hg[sy,sx,:] + b1) @ w2 + b2)[j] * gate[b,h,w]
//
// R2: two-kernel split.
//  - stage kernel (10KB LDS, high occupancy): hf = f @ w1_f (fp32) -> ws, gate -> ws,
//    hgb = h_g + b1 -> ws, w2^T bf16 -> ws (folded in, blocks 1..64).
//  - main kernel (32KB LDS only): per (b,h,16w): two halves of {phase A: hidden bf16
//    from global hf/hgb -> swizzled LDS, phase B: MFMA D[j][m] + gated stores}.
//    Barriers are raw s_barrier + lgkmcnt(0) only -> output stores stay in flight.

typedef __attribute__((ext_vector_type(8))) short bf16x8;
typedef __attribute__((ext_vector_type(4))) float f32x4;

__device__ inline short f2bf(float v) {
    __hip_bfloat16 b = __float2bfloat16(v);
    return *reinterpret_cast<short*>(&b);
}

__device__ inline void barrier_lgkm() {
    asm volatile("s_waitcnt lgkmcnt(0)" ::: "memory");
    __builtin_amdgcn_s_barrier();
    asm volatile("" ::: "memory");
}

// ---------------- stage kernel ----------------
__global__ __launch_bounds__(256, 4) void ipi_stage_kernel(
    const float* __restrict__ feat,     // (4,128,64,64)
    const float* __restrict__ gate_w1,  // (128,32)
    const float* __restrict__ gate_w2,  // (32,1)
    const float* __restrict__ gate_b2,  // (1,)
    const float* __restrict__ mlp_w1,   // (130,128)
    const float* __restrict__ mlp_b1,   // (128,)
    const float* __restrict__ w2,       // (128,128)
    float* __restrict__ hf_ws,          // (4*64*64, 128) fp32
    float* __restrict__ gate_ws,        // (4*64*64)
    float* __restrict__ hgb_ws,         // (16,128) fp32
    __hip_bfloat16* __restrict__ w2t)   // (128 j, 128 k) bf16
{
    __shared__ float f_tile[128 * 16];
    __shared__ float glds[16 * 32];

    const int t  = threadIdx.x;
    const int bx = blockIdx.x;
    const int w0 = (bx & 3) * 16;
    const int h  = (bx >> 2) & 63;
    const int b  = bx >> 8;

    // hgb (block 0) and w2^T (blocks 1..64) side work, no LDS involved
    if (bx == 0) {
        #pragma unroll
        for (int i = 0; i < 8; ++i) {
            int idx = t + i * 256;            // 2048 = 16s * 128k
            int s = idx >> 7, k = idx & 127;
            float cx = -0.75f + 0.5f * (float)(s & 3);
            float cy = -0.75f + 0.5f * (float)(s >> 2);
            hgb_ws[idx] = cx * mlp_w1[128 * 128 + k]
                        + cy * mlp_w1[129 * 128 + k]
                        + mlp_b1[k];
        }
    } else if (bx <= 64) {
        int gid = (bx - 1) * 256 + t;         // 16384 = 128j * 128k
        int j = gid >> 7, k = gid & 127;
        w2t[gid] = __float2bfloat16(w2[k * 128 + j]);
    }

    // stage f tile [c][w]
    {
        const float* fbase = feat + ((size_t)(b * 128) * 64 + h) * 64 + w0;
        #pragma unroll
        for (int i = 0; i < 8; ++i) {
            int idx = t + i * 256;            // 2048 = 128c * 16w
            int c = idx >> 4, w = idx & 15;
            f_tile[c * 16 + w] = fbase[(size_t)c * 4096 + w];
        }
    }
    __syncthreads();

    // gate hidden: g = leaky(f @ gate_w1)
    {
        int jg = t & 31, wq = t >> 5;
        float a0 = 0.f, a1 = 0.f;
        for (int c = 0; c < 128; ++c) {
            float gw = gate_w1[c * 32 + jg];
            a0 = fmaf(f_tile[c * 16 + wq], gw, a0);
            a1 = fmaf(f_tile[c * 16 + wq + 8], gw, a1);
        }
        glds[wq * 32 + jg]       = (a0 >= 0.f) ? a0 : 0.2f * a0;
        glds[(wq + 8) * 32 + jg] = (a1 >= 0.f) ? a1 : 0.2f * a1;
    }

    // hf[w][j] = f @ w1_f (fp32) -> ws
    {
        int j = t & 127, wb = t >> 7;
        float acc[8];
        #pragma unroll
        for (int i = 0; i < 8; ++i) acc[i] = 0.f;
        for (int c = 0; c < 128; ++c) {
            float wvv = mlp_w1[c * 128 + j];
            const float4* fp = (const float4*)&f_tile[c * 16 + wb * 8];
            float4 fa = fp[0], fb = fp[1];
            acc[0] = fmaf(fa.x, wvv, acc[0]);
            acc[1] = fmaf(fa.y, wvv, acc[1]);
            acc[2] = fmaf(fa.z, wvv, acc[2]);
            acc[3] = fmaf(fa.w, wvv, acc[3]);
            acc[4] = fmaf(fb.x, wvv, acc[4]);
            acc[5] = fmaf(fb.y, wvv, acc[5]);
            acc[6] = fmaf(fb.z, wvv, acc[6]);
            acc[7] = fmaf(fb.w, wvv, acc[7]);
        }
        float* hfb = hf_ws + ((size_t)((b * 64 + h) * 64) + w0 + wb * 8) * 128 + j;
        #pragma unroll
        for (int i = 0; i < 8; ++i) hfb[i * 128] = acc[i];
    }
    __syncthreads();

    // gate = sigmoid(g @ gate_w2 + b2) -> ws
    if (t < 16) {
        float s = gate_b2[0];
        for (int jg = 0; jg < 32; ++jg) s += glds[t * 32 + jg] * gate_w2[jg];
        gate_ws[(b * 64 + h) * 64 + w0 + t] = 1.f / (1.f + expf(-s));
    }
}

// ---------------- main kernel ----------------
__global__ __launch_bounds__(256, 4) void ipi_main_kernel(
    const __hip_bfloat16* __restrict__ w2t,  // (128j,128k) bf16
    const float* __restrict__ mlp_b2,        // (128,)
    const float* __restrict__ hf_ws,         // (4*64*64,128) fp32
    const float* __restrict__ gate_ws,       // (4*64*64)
    const float* __restrict__ hgb_ws,        // (16,128) fp32
    float* __restrict__ out)                 // (4,128,256,256)
{
    __shared__ char hid[32768];              // bf16 [128 m][128 k], XOR-swizzled

    const int t    = threadIdx.x;
    const int lane = t & 63;
    const int wv   = t >> 6;                 // wave -> j-range wv*32..+31
    const int bx   = blockIdx.x;
    const int w0   = (bx & 3) * 16;
    const int h    = (bx >> 2) & 63;
    const int b    = bx >> 8;

    // A-fragments (w2T rows) + b2
    bf16x8 afrag[2][4];
    f32x4  b2v[2];
    {
        const __hip_bfloat16* base = w2t + (wv * 32 + (lane & 15)) * 128 + (lane >> 4) * 8;
        #pragma unroll
        for (int jt = 0; jt < 2; ++jt) {
            #pragma unroll
            for (int ks = 0; ks < 4; ++ks)
                afrag[jt][ks] = *(const bf16x8*)(base + jt * 16 * 128 + ks * 32);
            b2v[jt] = *(const f32x4*)&mlp_b2[wv * 32 + jt * 16 + (lane >> 4) * 4];
        }
    }

    const float* hfbase = hf_ws + ((size_t)((b * 64 + h) * 64) + w0) * 128;
    const float* gbase  = gate_ws + (b * 64 + h) * 64 + w0;

    for (int half = 0; half < 2; ++half) {
        barrier_lgkm();   // hid free of previous phase-B readers (stores NOT drained)

        // phase A: hid[mh][k] = bf16(relu(hf[w][k] + hgb[s][k])) from GLOBAL
        {
            const int mh = t >> 1;
            const int w  = (mh >> 2) & 15;
            const int s  = (((half << 1) + (mh >> 6)) << 2) | (mh & 3);
            const float* hfr = hfbase + w * 128 + (t & 1) * 64;
            const float* hgr = hgb_ws + s * 128 + (t & 1) * 64;
            char* rowp = hid + mh * 256;
            const int kb0 = (t & 1) * 128;
            const int sw  = (mh & 7) << 4;
            #pragma unroll
            for (int kc = 0; kc < 8; ++kc) {
                float4 a0 = *(const float4*)(hfr + kc * 8);
                float4 a1 = *(const float4*)(hfr + kc * 8 + 4);
                float4 g0 = *(const float4*)(hgr + kc * 8);
                float4 g1 = *(const float4*)(hgr + kc * 8 + 4);
                bf16x8 hv;
                hv[0] = f2bf(fmaxf(a0.x + g0.x, 0.f));
                hv[1] = f2bf(fmaxf(a0.y + g0.y, 0.f));
                hv[2] = f2bf(fmaxf(a0.z + g0.z, 0.f));
                hv[3] = f2bf(fmaxf(a0.w + g0.w, 0.f));
                hv[4] = f2bf(fmaxf(a1.x + g1.x, 0.f));
                hv[5] = f2bf(fmaxf(a1.y + g1.y, 0.f));
                hv[6] = f2bf(fmaxf(a1.z + g1.z, 0.f));
                hv[7] = f2bf(fmaxf(a1.w + g1.w, 0.f));
                *(bf16x8*)(rowp + ((kb0 + kc * 16) ^ sw)) = hv;
            }
        }
        barrier_lgkm();   // hid visible; in-flight global stores unaffected

        // phase B: per wave D[j 32][m 128] via MFMA; gated+biased stores
        for (int mt = 0; mt < 8; ++mt) {
            const int mrow = mt * 16 + (lane & 15);
            const int swb  = (mrow & 7) << 4;
            const char* rowp = hid + mrow * 256;
            bf16x8 bfrag[4];
            #pragma unroll
            for (int ks = 0; ks < 4; ++ks)
                bfrag[ks] = *(const bf16x8*)(rowp + ((ks * 64 + (lane >> 4) * 16) ^ swb));

            f32x4 acc0 = {0.f, 0.f, 0.f, 0.f};
            f32x4 acc1 = {0.f, 0.f, 0.f, 0.f};
            #pragma unroll
            for (int ks = 0; ks < 4; ++ks) {
                acc0 = __builtin_amdgcn_mfma_f32_16x16x32_bf16(afrag[0][ks], bfrag[ks], acc0, 0, 0, 0);
                acc1 = __builtin_amdgcn_mfma_f32_16x16x32_bf16(afrag[1][ks], bfrag[ks], acc1, 0, 0, 0);
            }

            const int m  = (half << 7) + mrow;
            const int sy = m >> 6;
            const float g = gbase[(m >> 2) & 15];
            float* outp = out + ((size_t)(b * 128 + wv * 32 + (lane >> 4) * 4) << 16)
                              + (size_t)(h * 4 + sy) * 256 + w0 * 4 + (m & 63);
            #pragma unroll
            for (int r = 0; r < 4; ++r) {
                outp[(size_t)r << 16]        = (acc0[r] + b2v[0][r]) * g;
                outp[(size_t)(r + 16) << 16] = (acc1[r] + b2v[1][r]) * g;
            }
        }
    }
}

// ---------------- fallback (R1 mono kernel) ----------------
__global__ __launch_bounds__(256) void w2t_kernel(const float* __restrict__ w2,
                                                  __hip_bfloat16* __restrict__ w2t) {
    __shared__ float tile[16][17];
    const int kt = (blockIdx.x & 7) * 16, jt = (blockIdx.x >> 3) * 16;
    const int tx = threadIdx.x & 15, ty = threadIdx.x >> 4;
    tile[ty][tx] = w2[(kt + ty) * 128 + jt + tx];
    __syncthreads();
    w2t[(jt + ty) * 128 + kt + tx] = __float2bfloat16(tile[tx][ty]);
}

__global__ __launch_bounds__(256, 3) void ipi_mono_kernel(
    const float* __restrict__ feat, const float* __restrict__ gate_w1,
    const float* __restrict__ gate_w2, const float* __restrict__ gate_b2,
    const float* __restrict__ mlp_w1, const float* __restrict__ mlp_b1,
    const float* __restrict__ mlp_b2, const __hip_bfloat16* __restrict__ w2t,
    float* __restrict__ out)
{
    __shared__ float hf[16 * 132];
    __shared__ float hgb[16 * 132];
    __shared__ float gate_s[16];
    __shared__ char  hid[32768];
    float* f_tile = (float*)hid;
    float* glds   = (float*)(hid + 8192);

    const int t    = threadIdx.x;
    const int lane = t & 63;
    const int wv   = t >> 6;
    const int bx   = blockIdx.x;
    const int w0   = (bx & 3) * 16;
    const int h    = (bx >> 2) & 63;
    const int b    = bx >> 8;

    bf16x8 afrag[2][4];
    f32x4  b2v[2];
    {
        const __hip_bfloat16* base = w2t + (wv * 32 + (lane & 15)) * 128 + (lane >> 4) * 8;
        #pragma unroll
        for (int jt = 0; jt < 2; ++jt) {
            #pragma unroll
            for (int ks = 0; ks < 4; ++ks)
                afrag[jt][ks] = *(const bf16x8*)(base + jt * 16 * 128 + ks * 32);
            b2v[jt] = *(const f32x4*)&mlp_b2[wv * 32 + jt * 16 + (lane >> 4) * 4];
        }
    }
    {
        const float* fbase = feat + ((size_t)(b * 128) * 64 + h) * 64 + w0;
        #pragma unroll
        for (int i = 0; i < 8; ++i) {
            int idx = t + i * 256;
            int c = idx >> 4, w = idx & 15;
            f_tile[c * 16 + w] = fbase[(size_t)c * 4096 + w];
        }
        #pragma unroll
        for (int i = 0; i < 8; ++i) {
            int idx = t + i * 256;
            int s = idx >> 7, k = idx & 127;
            float cx = -0.75f + 0.5f * (float)(s & 3);
            float cy = -0.75f + 0.5f * (float)(s >> 2);
            hgb[s * 132 + k] = cx * mlp_w1[128 * 128 + k]
                             + cy * mlp_w1[129 * 128 + k] + mlp_b1[k];
        }
    }
    __syncthreads();
    {
        int jg = t & 31, wq = t >> 5;
        float a0 = 0.f, a1 = 0.f;
        for (int c = 0; c < 128; ++c) {
            float gw = gate_w1[c * 32 + jg];
            a0 = fmaf(f_tile[c * 16 + wq], gw, a0);
            a1 = fmaf(f_tile[c * 16 + wq + 8], gw, a1);
        }
        glds[wq * 32 + jg]       = (a0 >= 0.f) ? a0 : 0.2f * a0;
        glds[(wq + 8) * 32 + jg] = (a1 >= 0.f) ? a1 : 0.2f * a1;
    }
    {
        int j = t & 127, wb = t >> 7;
        float acc[8];
        #pragma unroll
        for (int i = 0; i < 8; ++i) acc[i] = 0.f;
        for (int c = 0; c < 128; ++c) {
            float wvv = mlp_w1[c * 128 + j];
            const float4* fp = (const float4*)&f_tile[c * 16 + wb * 8];
            float4 fa = fp[0], fb = fp[1];
            acc[0] = fmaf(fa.x, wvv, acc[0]);
            acc[1] = fmaf(fa.y, wvv, acc[1]);
            acc[2] = fmaf(fa.z, wvv, acc[2]);
            acc[3] = fmaf(fa.w, wvv, acc[3]);
            acc[4] = fmaf(fb.x, wvv, acc[4]);
            acc[5] = fmaf(fb.y, wvv, acc[5]);
            acc[6] = fmaf(fb.z, wvv, acc[6]);
            acc[7] = fmaf(fb.w, wvv, acc[7]);
        }
        #pragma unroll
        for (int i = 0; i < 8; ++i) hf[(wb * 8 + i) * 132 + j] = acc[i];
    }
    __syncthreads();
    if (t < 16) {
        float s = gate_b2[0];
        for (int jg = 0; jg < 32; ++jg) s += glds[t * 32 + jg] * gate_w2[jg];
        gate_s[t] = 1.f / (1.f + expf(-s));
    }
    for (int half = 0; half < 2; ++half) {
        __syncthreads();
        {
            const int mh = t >> 1;
            const int w  = (mh >> 2) & 15;
            const int s  = ((((half << 7) + mh) >> 6) << 2) | (mh & 3);
            const float* hfr = hf  + w * 132 + (t & 1) * 64;
            const float* hgr = hgb + s * 132 + (t & 1) * 64;
            char* rowp = hid + mh * 256;
            const int kb0 = (t & 1) * 128;
            const int sw  = (mh & 7) << 4;
            #pragma unroll
            for (int kc = 0; kc < 8; ++kc) {
                float4 a0 = *(const float4*)(hfr + kc * 8);
                float4 a1 = *(const float4*)(hfr + kc * 8 + 4);
                float4 g0 = *(const float4*)(hgr + kc * 8);
                float4 g1 = *(const float4*)(hgr + kc * 8 + 4);
                bf16x8 hv;
                hv[0] = f2bf(fmaxf(a0.x + g0.x, 0.f));
                hv[1] = f2bf(fmaxf(a0.y + g0.y, 0.f));
                hv[2] = f2bf(fmaxf(a0.z + g0.z, 0.f));
                hv[3] = f2bf(fmaxf(a0.w + g0.w, 0.f));
                hv[4] = f2bf(fmaxf(a1.x + g1.x, 0.f));
                hv[5] = f2bf(fmaxf(a1.y + g1.y, 0.f));
                hv[6] = f2bf(fmaxf(a1.z + g1.z, 0.f));
                hv[7] = f2bf(fmaxf(a1.w + g1.w, 0.f));
                *(bf16x8*)(rowp + ((kb0 + kc * 16) ^ sw)) = hv;
            }
        }
        __syncthreads();
        for (int mt = 0; mt < 8; ++mt) {
            const int mrow = mt * 16 + (lane & 15);
            const int swb  = (mrow & 7) << 4;
            const char* rowp = hid + mrow * 256;
            bf16x8 bfrag[4];
            #pragma unroll
            for (int ks = 0; ks < 4; ++ks)
                bfrag[ks] = *(const bf16x8*)(rowp + ((ks * 64 + (lane >> 4) * 16) ^ swb));
            f32x4 acc0 = {0.f, 0.f, 0.f, 0.f};
            f32x4 acc1 = {0.f, 0.f, 0.f, 0.f};
            #pragma unroll
            for (int ks = 0; ks < 4; ++ks) {
                acc0 = __builtin_amdgcn_mfma_f32_16x16x32_bf16(afrag[0][ks], bfrag[ks], acc0, 0, 0, 0);
                acc1 = __builtin_amdgcn_mfma_f32_16x16x32_bf16(afrag[1][ks], bfrag[ks], acc1, 0, 0, 0);
            }
            const int m  = (half << 7) + mrow;
            const int sy = m >> 6;
            const float g = gate_s[(m >> 2) & 15];
            float* outp = out + ((size_t)(b * 128 + wv * 32 + (lane >> 4) * 4) << 16)
                              + (size_t)(h * 4 + sy) * 256 + w0 * 4 + (m & 63);
            #pragma unroll
            for (int r = 0; r < 4; ++r) {
                outp[(size_t)r << 16]        = (acc0[r] + b2v[0][r]) * g;
                outp[(size_t)(r + 16) << 16] = (acc1[r] + b2v[1][r]) * g;
            }
        }
    }
}

extern "C" void kernel_launch(void* const* d_in, const int* in_sizes, int n_in,
                              void* d_out, int out_size, void* d_ws, size_t ws_size,
                              hipStream_t stream) {
    const float* feat = (const float*)d_in[0];
    const float* gw1  = (const float*)d_in[1];
    const float* gw2  = (const float*)d_in[2];
    const float* gb2  = (const float*)d_in[3];
    const float* w1   = (const float*)d_in[4];
    const float* b1   = (const float*)d_in[5];
    const float* w2   = (const float*)d_in[6];
    const float* b2   = (const float*)d_in[7];
    float* o = (float*)d_out;

    // ws layout: [w2t bf16 32KB][hf fp32 8MB][gate fp32 64KB][hgb fp32 8KB]
    const size_t OFF_HF   = 32768;
    const size_t OFF_GATE = OFF_HF + (size_t)4 * 64 * 64 * 128 * 4;
    const size_t OFF_HGB  = OFF_GATE + (size_t)4 * 64 * 64 * 4;
    const size_t NEED     = OFF_HGB + 16 * 128 * 4;

    char* ws = (char*)d_ws;
    __hip_bfloat16* w2t = (__hip_bfloat16*)ws;

    if (ws_size >= NEED) {
        float* hf_ws   = (float*)(ws + OFF_HF);
        float* gate_ws = (float*)(ws + OFF_GATE);
        float* hgb_ws  = (float*)(ws + OFF_HGB);
        ipi_stage_kernel<<<dim3(1024), dim3(256), 0, stream>>>(
            feat, gw1, gw2, gb2, w1, b1, w2, hf_ws, gate_ws, hgb_ws, w2t);
        ipi_main_kernel<<<dim3(1024), dim3(256), 0, stream>>>(
            w2t, b2, hf_ws, gate_ws, hgb_ws, o);
    } else {
        w2t_kernel<<<dim3(64), dim3(256), 0, stream>>>(w2, w2t);
        ipi_mono_kernel<<<dim3(1024), dim3(256), 0, stream>>>(
            feat, gw1, gw2, gb2, w1, b1, b2, w2t, o);
    }
}

// Round 4
// 44.362 us; speedup vs baseline: 1.4873x; 1.4873x over previous
//
#include <hip/hip_runtime.h>
#include <hip/hip_bf16.h>
#include <math.h>

// ImplicitPolygonInjector: B=4, C=128, H=W=64, S=4
// out[b][j][h*4+sy][w*4+sx] = (relu(hf[b,h,w,:]+hg[sy,sx,:]+b1) @ w2 + b2)[j] * gate[b,h,w]
//
// R3: mono kernel, steady-state loop has NO global loads -> lgkm-only barriers
// never drain output stores (vmcnt is in-order; any global load wait would).
// hf = f@w1_f and gate GEMV both moved to split-bf16 (hi+lo) MFMA.
// Pre-kernel: w2^T, w1_f^T(hi,lo), gate_w1^T(hi,lo) as bf16 in d_ws.
// Per block: (b,h,16w). Quarters of 64 m rows (hid 16KB) -> 33.4KB LDS, 4 blocks/CU.

typedef __attribute__((ext_vector_type(8))) short bf16x8;
typedef __attribute__((ext_vector_type(4))) float f32x4;

__device__ inline short f2bf(float v) {
    __hip_bfloat16 b = __float2bfloat16(v);
    return *reinterpret_cast<short*>(&b);
}

__device__ inline void barrier_lgkm() {
    asm volatile("s_waitcnt lgkmcnt(0)" ::: "memory");
    __builtin_amdgcn_s_barrier();
    asm volatile("" ::: "memory");
}

// ---------------- pre-kernel: transposes + bf16 hi/lo split ----------------
__global__ __launch_bounds__(256) void ipi_pre_kernel(
    const float* __restrict__ w2,    // (128,128)
    const float* __restrict__ w1,    // (130,128) -- rows 0..127 used
    const float* __restrict__ gw1,   // (128,32)
    __hip_bfloat16* __restrict__ w2t,     // (128j,128k)
    __hip_bfloat16* __restrict__ w1t_hi,  // (128j,128c)
    __hip_bfloat16* __restrict__ w1t_lo,
    __hip_bfloat16* __restrict__ g1t_hi,  // (32jg,128c)
    __hip_bfloat16* __restrict__ g1t_lo)
{
    int gid = blockIdx.x * 256 + threadIdx.x;
    if (gid < 16384) {
        int j = gid >> 7, k = gid & 127;
        w2t[gid] = __float2bfloat16(w2[k * 128 + j]);
    } else if (gid < 32768) {
        int i = gid - 16384, j = i >> 7, c = i & 127;
        float v = w1[c * 128 + j];
        __hip_bfloat16 hi = __float2bfloat16(v);
        w1t_hi[i] = hi;
        w1t_lo[i] = __float2bfloat16(v - __bfloat162float(hi));
    } else if (gid < 36864) {
        int i = gid - 32768, jg = i >> 7, c = i & 127;
        float v = gw1[c * 32 + jg];
        __hip_bfloat16 hi = __float2bfloat16(v);
        g1t_hi[i] = hi;
        g1t_lo[i] = __float2bfloat16(v - __bfloat162float(hi));
    }
}

// ---------------- main kernel ----------------
__global__ __launch_bounds__(256, 4) void ipi_main(
    const float* __restrict__ feat,     // (4,128,64,64)
    const float* __restrict__ mlp_w1,   // (130,128) -- rows 128,129 for grid coords
    const float* __restrict__ mlp_b1,   // (128,)
    const float* __restrict__ gate_w2,  // (32,)
    const float* __restrict__ gate_b2,  // (1,)
    const float* __restrict__ mlp_b2,   // (128,)
    const __hip_bfloat16* __restrict__ w2t,
    const __hip_bfloat16* __restrict__ w1t_hi,
    const __hip_bfloat16* __restrict__ w1t_lo,
    const __hip_bfloat16* __restrict__ g1t_hi,
    const __hip_bfloat16* __restrict__ g1t_lo,
    float* __restrict__ out)            // (4,128,256,256)
{
    __shared__ float hf_s[16 * 132];    // hf[w][j] fp32, 8448 B
    __shared__ float hgb_s[16 * 132];   // hgb[s][k] fp32, 8448 B
    __shared__ float gate_s[16];
    __shared__ char  hid[16384];        // bf16 [64 m][128 k] swizzled (per quarter)
    short* f_hi = (short*)hid;          // [16 w][136 c] bf16 (prologue only)
    short* f_lo = (short*)(hid + 4352);
    float* glds = (float*)(hid + 8704); // [16 w][33 jg] fp32 (prologue only)

    const int t    = threadIdx.x;
    const int lane = t & 63;
    const int lg   = lane >> 4;         // 0..3
    const int ml   = lane & 15;
    const int wv   = t >> 6;            // wave id -> j-range wv*32..+31
    const int bx   = blockIdx.x;
    const int w0   = (bx & 3) * 16;
    const int h    = (bx >> 2) & 63;
    const int b    = bx >> 8;

    // ---- w2t A-frags + b2 (global, prologue) ----
    bf16x8 afrag[2][4];
    f32x4  b2v[2];
    {
        const __hip_bfloat16* base = w2t + (wv * 32 + ml) * 128 + lg * 8;
        #pragma unroll
        for (int jt = 0; jt < 2; ++jt) {
            #pragma unroll
            for (int ks = 0; ks < 4; ++ks)
                afrag[jt][ks] = *(const bf16x8*)(base + jt * 2048 + ks * 32);
            b2v[jt] = *(const f32x4*)&mlp_b2[wv * 32 + jt * 16 + lg * 4];
        }
    }

    // ---- stage f (transposed, bf16 hi/lo) + hgb ----
    {
        const float* fbase = feat + ((size_t)(b * 128) * 64 + h) * 64 + w0;
        #pragma unroll
        for (int i = 0; i < 8; ++i) {
            int idx = t + i * 256;            // 2048 = 128c * 16w
            int c = idx >> 4, w = idx & 15;
            float v = fbase[(size_t)c * 4096 + w];
            short hi = f2bf(v);
            float hf32 = __bfloat162float(*(__hip_bfloat16*)&hi);
            f_hi[w * 136 + c] = hi;
            f_lo[w * 136 + c] = f2bf(v - hf32);
        }
        #pragma unroll
        for (int i = 0; i < 8; ++i) {
            int idx = t + i * 256;            // 2048 = 16s * 128k
            int s = idx >> 7, k = idx & 127;
            float cx = -0.75f + 0.5f * (float)(s & 3);
            float cy = -0.75f + 0.5f * (float)(s >> 2);
            hgb_s[s * 132 + k] = cx * mlp_w1[16384 + k]
                               + cy * mlp_w1[16512 + k] + mlp_b1[k];
        }
    }
    barrier_lgkm();

    // ---- hf = f @ w1_f via split-bf16 MFMA (all waves); gate MFMA (wave 0) ----
    {
        bf16x8 fhi[4], flo[4];
        {
            const short* fb  = f_hi + ml * 136 + lg * 8;
            const short* flb = f_lo + ml * 136 + lg * 8;
            #pragma unroll
            for (int ks = 0; ks < 4; ++ks) {
                fhi[ks] = *(const bf16x8*)(fb + ks * 32);
                flo[ks] = *(const bf16x8*)(flb + ks * 32);
            }
        }
        #pragma unroll
        for (int jj = 0; jj < 2; ++jj) {
            const int jt16 = (wv * 2 + jj) * 16;
            const __hip_bfloat16* bh = w1t_hi + (jt16 + ml) * 128 + lg * 8;
            const __hip_bfloat16* bl = w1t_lo + (jt16 + ml) * 128 + lg * 8;
            f32x4 acc = {0.f, 0.f, 0.f, 0.f};
            #pragma unroll
            for (int ks = 0; ks < 4; ++ks) {
                bf16x8 Bh = *(const bf16x8*)(bh + ks * 32);
                bf16x8 Bl = *(const bf16x8*)(bl + ks * 32);
                acc = __builtin_amdgcn_mfma_f32_16x16x32_bf16(fhi[ks], Bh, acc, 0, 0, 0);
                acc = __builtin_amdgcn_mfma_f32_16x16x32_bf16(fhi[ks], Bl, acc, 0, 0, 0);
                acc = __builtin_amdgcn_mfma_f32_16x16x32_bf16(flo[ks], Bh, acc, 0, 0, 0);
            }
            // D[w = lg*4+r][j = jt16+ml]
            #pragma unroll
            for (int r = 0; r < 4; ++r)
                hf_s[(lg * 4 + r) * 132 + jt16 + ml] = acc[r];
        }
        if (wv == 0) {
            #pragma unroll
            for (int jt = 0; jt < 2; ++jt) {
                const __hip_bfloat16* bh = g1t_hi + (jt * 16 + ml) * 128 + lg * 8;
                const __hip_bfloat16* bl = g1t_lo + (jt * 16 + ml) * 128 + lg * 8;
                f32x4 acc = {0.f, 0.f, 0.f, 0.f};
                #pragma unroll
                for (int ks = 0; ks < 4; ++ks) {
                    bf16x8 Bh = *(const bf16x8*)(bh + ks * 32);
                    bf16x8 Bl = *(const bf16x8*)(bl + ks * 32);
                    acc = __builtin_amdgcn_mfma_f32_16x16x32_bf16(fhi[ks], Bh, acc, 0, 0, 0);
                    acc = __builtin_amdgcn_mfma_f32_16x16x32_bf16(fhi[ks], Bl, acc, 0, 0, 0);
                    acc = __builtin_amdgcn_mfma_f32_16x16x32_bf16(flo[ks], Bh, acc, 0, 0, 0);
                }
                #pragma unroll
                for (int r = 0; r < 4; ++r) {
                    float v = acc[r];
                    glds[(lg * 4 + r) * 33 + jt * 16 + ml] = (v >= 0.f) ? v : 0.2f * v;
                }
            }
        }
    }
    barrier_lgkm();

    // ---- gate = sigmoid(g @ gate_w2 + b2) ----
    if (t < 16) {
        float s = gate_b2[0];
        #pragma unroll 8
        for (int jg = 0; jg < 32; ++jg) s = fmaf(glds[t * 33 + jg], gate_w2[jg], s);
        gate_s[t] = 1.f / (1.f + expf(-s));
    }
    barrier_lgkm();

    // ---- steady state: 4 quarters (sy = q), pure LDS + MFMA + stores ----
    const int mq  = t >> 2;             // 0..63: m-row in quarter (= out col)
    const int wA  = mq >> 2;            // 0..15
    const int sxA = mq & 3;
    const int kq  = t & 3;              // k-chunk (32 k each)
    for (int q = 0; q < 4; ++q) {
        // phase A: hid[mq][k] = bf16(relu(hf[wA][k] + hgb[q*4+sxA][k]))
        {
            const float* hfr = hf_s  + wA * 132 + kq * 32;
            const float* hgr = hgb_s + (q * 4 + sxA) * 132 + kq * 32;
            char* rowp = hid + mq * 256;
            const int sw = (mq & 7) << 4;
            #pragma unroll
            for (int kc = 0; kc < 4; ++kc) {
                float4 a0 = *(const float4*)(hfr + kc * 8);
                float4 a1 = *(const float4*)(hfr + kc * 8 + 4);
                float4 g0 = *(const float4*)(hgr + kc * 8);
                float4 g1 = *(const float4*)(hgr + kc * 8 + 4);
                bf16x8 hv;
                hv[0] = f2bf(fmaxf(a0.x + g0.x, 0.f));
                hv[1] = f2bf(fmaxf(a0.y + g0.y, 0.f));
                hv[2] = f2bf(fmaxf(a0.z + g0.z, 0.f));
                hv[3] = f2bf(fmaxf(a0.w + g0.w, 0.f));
                hv[4] = f2bf(fmaxf(a1.x + g1.x, 0.f));
                hv[5] = f2bf(fmaxf(a1.y + g1.y, 0.f));
                hv[6] = f2bf(fmaxf(a1.z + g1.z, 0.f));
                hv[7] = f2bf(fmaxf(a1.w + g1.w, 0.f));
                *(bf16x8*)(rowp + ((kq * 64 + kc * 16) ^ sw)) = hv;
            }
        }
        barrier_lgkm();

        // phase B: D[j 32][m 64] via MFMA; gated+biased scalar stores (no drains)
        #pragma unroll
        for (int mt = 0; mt < 4; ++mt) {
            const int mrow = mt * 16 + ml;      // 0..63
            const int swb  = (mrow & 7) << 4;
            const char* rowp = hid + mrow * 256;
            bf16x8 bfrag[4];
            #pragma unroll
            for (int ks = 0; ks < 4; ++ks)
                bfrag[ks] = *(const bf16x8*)(rowp + ((ks * 64 + lg * 16) ^ swb));

            f32x4 acc0 = {0.f, 0.f, 0.f, 0.f};
            f32x4 acc1 = {0.f, 0.f, 0.f, 0.f};
            #pragma unroll
            for (int ks = 0; ks < 4; ++ks) {
                acc0 = __builtin_amdgcn_mfma_f32_16x16x32_bf16(afrag[0][ks], bfrag[ks], acc0, 0, 0, 0);
                acc1 = __builtin_amdgcn_mfma_f32_16x16x32_bf16(afrag[1][ks], bfrag[ks], acc1, 0, 0, 0);
            }

            const float g = gate_s[mrow >> 2];
            float* outp = out + ((size_t)(b * 128 + wv * 32 + lg * 4) << 16)
                              + (size_t)(h * 4 + q) * 256 + w0 * 4 + mrow;
            #pragma unroll
            for (int r = 0; r < 4; ++r) {
                outp[(size_t)r << 16]        = (acc0[r] + b2v[0][r]) * g;
                outp[(size_t)(r + 16) << 16] = (acc1[r] + b2v[1][r]) * g;
            }
        }
        barrier_lgkm();
    }
}

extern "C" void kernel_launch(void* const* d_in, const int* in_sizes, int n_in,
                              void* d_out, int out_size, void* d_ws, size_t ws_size,
                              hipStream_t stream) {
    const float* feat = (const float*)d_in[0];
    const float* gw1  = (const float*)d_in[1];
    const float* gw2  = (const float*)d_in[2];
    const float* gb2  = (const float*)d_in[3];
    const float* w1   = (const float*)d_in[4];
    const float* b1   = (const float*)d_in[5];
    const float* w2   = (const float*)d_in[6];
    const float* b2   = (const float*)d_in[7];
    float* o = (float*)d_out;

    // ws: w2t 32K | w1t_hi 32K | w1t_lo 32K | g1t_hi 8K | g1t_lo 8K  = 112K
    char* ws = (char*)d_ws;
    __hip_bfloat16* w2t    = (__hip_bfloat16*)(ws);
    __hip_bfloat16* w1t_hi = (__hip_bfloat16*)(ws + 32768);
    __hip_bfloat16* w1t_lo = (__hip_bfloat16*)(ws + 65536);
    __hip_bfloat16* g1t_hi = (__hip_bfloat16*)(ws + 98304);
    __hip_bfloat16* g1t_lo = (__hip_bfloat16*)(ws + 106496);

    ipi_pre_kernel<<<dim3(144), dim3(256), 0, stream>>>(
        w2, w1, gw1, w2t, w1t_hi, w1t_lo, g1t_hi, g1t_lo);
    ipi_main<<<dim3(1024), dim3(256), 0, stream>>>(
        feat, w1, b1, gw2, gb2, b2, w2t, w1t_hi, w1t_lo, g1t_hi, g1t_lo, o);
}